// Round 4
// baseline (48.975 us; speedup 1.0000x reference)
//
#include <hip/hip_runtime.h>

// VectorQuantizer on MI355X (gfx950) — v4.
// out[0 .. 8388607] = codebook[argmin_k ||z - E_k||^2]   (f32)
// out[8388608]      = 1.25 * mean((z_q - z)^2)           (f32)
//
// Score: maximize  s + ca  where s = z.(1024 E_k) (bf16 MFMA), ca = 128 -
// ||1024 E_k||^2/2048 fed as the MFMA C-operand.  Key = (bits(s+ca) &
// 0xFFFFFC00) | (1023-col); u32 max = argmax + earliest-col tie-break.
// Loss fused: ||q-z||^2_row = ||z||^2 + (128 - v*)/512.
//
// v4 structure: 4-wave block owns 128 rows; ALL waves share the same A
// (staged once in LDS, f32, XOR-swizzled) and split each 64-code B stage in
// half by wave (wc) -> 4x less LDS read traffic than v3.  B staging uses a
// 4-buffer ring with counted `s_waitcnt vmcnt(4)` + raw s_barrier (loads stay
// in flight across barriers; no vmcnt(0) drain in the main loop).  Winners
// u32-max-combined across the wc pair through LDS; gather + out-write +
// loss fused in the epilogue.

typedef __attribute__((ext_vector_type(8))) short bf16x8;
typedef __attribute__((ext_vector_type(4))) float f32x4;

#define N_TOKENS 131072
#define DIM 64

__device__ __forceinline__ short f32_bf16(float f) {
  unsigned u = __builtin_bit_cast(unsigned, f);
  unsigned r = u + 0x7FFFu + ((u >> 16) & 1u);   // round-to-nearest-even
  return (short)(r >> 16);
}

// ---------------- kernel 1: codebook prep -------------------------------------
__global__ __launch_bounds__(256) void vq_prep(
    const float* __restrict__ cb, unsigned short* __restrict__ ch,
    float* __restrict__ ca2, double* __restrict__ accum) {
  const int lane = threadIdx.x & 63;
  const int wv = threadIdx.x >> 6;
  const int code = blockIdx.x * 4 + wv;      // 256 blocks * 4 waves = 1024 codes
  const float e = cb[code * DIM + lane] * 1024.0f;   // exact pow2 scale
  ch[code * DIM + lane] = (unsigned short)f32_bf16(e);
  float sq = e * e;
  #pragma unroll
  for (int w = 32; w >= 1; w >>= 1) sq += __shfl_xor(sq, w, 64);
  if (lane == 0) ca2[code] = 128.0f - sq * (1.0f / 2048.0f);
  if (blockIdx.x == 0 && threadIdx.x == 0) *accum = 0.0;
}

// ---------------- kernel 2: fused score + argmin + gather + loss --------------
__global__ __launch_bounds__(256, 4) void vq_argmin(
    const float* __restrict__ z, const unsigned short* __restrict__ ch,
    const float* __restrict__ ca2, const float* __restrict__ cb,
    float* __restrict__ out, double* __restrict__ accum) {
  __shared__ unsigned short Bs[4][4096];   // 32 KB: B ring; aliased as A (f32) in prologue
  __shared__ float ca_s[1024];             // 4 KB: ca table (LDS so loop stays vmcnt-clean)
  __shared__ unsigned smw[2][128];         // per-wc winners per row
  __shared__ float smz[2];                 // per-wr sum(z^2)
  __shared__ float sml[4];                 // per-wave loss partials

  const int tid = threadIdx.x, lane = tid & 63, wv = tid >> 6;
  const int g = lane >> 4, c15 = lane & 15, sw = c15 & 7;
  const int wr = wv >> 1, wc = wv & 1;     // row-half / code-half of this wave
  const size_t rowblk = (size_t)blockIdx.x * 128;
  unsigned short* bsflat = (unsigned short*)Bs;

  // ---- prologue: stage A (128 rows f32, source-XOR-swizzled) + ca into LDS
  {
    const float* zb = z + rowblk * DIM;
    #pragma unroll
    for (int q = 0; q < 8; ++q) {
      const int L = q * 256 + tid;               // 16B chunk id, 0..2047
      const int row = L >> 4, c = L & 15;
      const float* src = zb + row * DIM + ((c ^ (row & 15)) << 2);
      __builtin_amdgcn_global_load_lds(
          (const __attribute__((address_space(1))) unsigned int*)src,
          (__attribute__((address_space(3))) unsigned int*)
              (bsflat + (q * 256 + wv * 64) * 8),
          16, 0, 0);
    }
    __builtin_amdgcn_global_load_lds(
        (const __attribute__((address_space(1))) unsigned int*)(ca2 + tid * 4),
        (__attribute__((address_space(3))) unsigned int*)&ca_s[wv * 256],
        16, 0, 0);
  }
  __syncthreads();   // full drain (once): A + ca resident

  // ---- extract A fragments (rows wr*64..+64, all dims) + zsq (exact f32)
  bf16x8 ah[4][2];
  float zsq = 0.0f;
  const float* Af = (const float*)Bs;
  #pragma unroll
  for (int m = 0; m < 4; ++m) {
    const int row = wr * 64 + m * 16 + c15;      // row & 15 == c15
    #pragma unroll
    for (int kk = 0; kk < 2; ++kk) {
      const int c0 = kk * 8 + g * 2;
      const f32x4 v0 = *(const f32x4*)(Af + ((row << 4) + (c0 ^ c15)) * 4);
      const f32x4 v1 = *(const f32x4*)(Af + ((row << 4) + ((c0 + 1) ^ c15)) * 4);
      #pragma unroll
      for (int j = 0; j < 4; ++j) {
        ah[m][kk][j]     = f32_bf16(v0[j]);
        ah[m][kk][j + 4] = f32_bf16(v1[j]);
        zsq += v0[j] * v0[j] + v1[j] * v1[j];
      }
    }
  }
  if (wc == 0) {     // both wc waves see the same rows; count once
    float t = zsq;
    #pragma unroll
    for (int w = 32; w >= 1; w >>= 1) t += __shfl_xor(t, w, 64);
    if (lane == 0) smz[wr] = t;
  }
  __syncthreads();   // A fully consumed -> Bs reusable as B ring

  // ---- B staging: 4-buffer ring, counted vmcnt (T4), prefetch depth 3
  int soff[2];
  #pragma unroll
  for (int q = 0; q < 2; ++q) {
    const int L = q * 256 + tid;                 // chunk id within a stage
    const int code = L >> 3, c = L & 7;
    soff[q] = code * DIM + ((c ^ (code & 7)) << 3);   // source-side XOR swizzle
  }
  auto stageB = [&](int s) {
    const int b = s & 3;
    #pragma unroll
    for (int q = 0; q < 2; ++q)
      __builtin_amdgcn_global_load_lds(
          (const __attribute__((address_space(1))) unsigned int*)
              (ch + s * 4096 + soff[q]),
          (__attribute__((address_space(3))) unsigned int*)
              (bsflat + b * 4096 + (q * 256 + wv * 64) * 8),
          16, 0, 0);
  };
  stageB(0); stageB(1); stageB(2);               // 6 loads in flight

  unsigned best[4][4];
  #pragma unroll
  for (int m = 0; m < 4; ++m)
    #pragma unroll
    for (int r = 0; r < 4; ++r) best[m][r] = 0u;

  const unsigned kmask = 0xFFFFFC00u;
  const unsigned ccb = 1023u - (unsigned)(wc * 32 + c15);
  const char* bsp = (const char*)Bs;
  const int boff0 = (wc * 32 + c15) * 128;       // this wave's code half
  const int bx0 = (g ^ sw) << 4;                 // kk=0 chunk (swizzled)
  const int bx1 = ((4 + g) ^ sw) << 4;           // kk=1 chunk (swizzled)

  #pragma unroll 1
  for (int s = 0; s < 16; ++s) {
    // wait for stage s's own loads (leave s+1,s+2 in flight), then barrier
    if (s < 14)       asm volatile("s_waitcnt vmcnt(4)" ::: "memory");
    else if (s == 14) asm volatile("s_waitcnt vmcnt(2)" ::: "memory");
    else              asm volatile("s_waitcnt vmcnt(0)" ::: "memory");
    __builtin_amdgcn_s_barrier();
    if (s < 13) stageB(s + 3);    // overwrites buf[(s-1)&3]: safe post-barrier
    const int b = s & 3;
    const unsigned cc_s = ccb - (unsigned)(s * 64);
    #pragma unroll
    for (int n = 0; n < 2; ++n) {
      const float can = ca_s[s * 64 + wc * 32 + n * 16 + c15];
      const bf16x8 bf0 = *(const bf16x8*)(bsp + b * 8192 + boff0 + n * 2048 + bx0);
      const bf16x8 bf1 = *(const bf16x8*)(bsp + b * 8192 + boff0 + n * 2048 + bx1);
      const f32x4 cv = {can, can, can, can};     // MFMA C-init: no per-acc movs
      const unsigned cc = cc_s - (unsigned)(n * 16);
      #pragma unroll
      for (int m = 0; m < 4; ++m) {
        f32x4 acc = __builtin_amdgcn_mfma_f32_16x16x32_bf16(
            ah[m][0], bf0, cv, 0, 0, 0);
        acc = __builtin_amdgcn_mfma_f32_16x16x32_bf16(
            ah[m][1], bf1, acc, 0, 0, 0);
        #pragma unroll
        for (int r = 0; r < 4; ++r) {
          const unsigned key =
              (__builtin_bit_cast(unsigned, acc[r]) & kmask) | cc;
          best[m][r] = key > best[m][r] ? key : best[m][r];   // v_max_u32
        }
      }
    }
  }

  // ---- winners: butterfly over the 16 c15 lanes, publish per-wc to LDS
  #pragma unroll
  for (int m = 0; m < 4; ++m)
    #pragma unroll
    for (int r = 0; r < 4; ++r) {
      unsigned bk = best[m][r];
      #pragma unroll
      for (int w = 1; w < 16; w <<= 1) {
        const unsigned ob = (unsigned)__shfl_xor((int)bk, w, 64);
        bk = ob > bk ? ob : bk;
      }
      if (c15 == 0) smw[wc][wr * 64 + m * 16 + g * 4 + r] = bk;
    }
  __syncthreads();

  // ---- combine wc halves, gather codebook row -> out, loss partials
  {
    const int row_l = tid >> 1, half = tid & 1;
    const unsigned k0 = smw[0][row_l], k1 = smw[1][row_l];
    const unsigned kf = k0 > k1 ? k0 : k1;
    const int bi = 1023 - (int)(kf & 1023u);
    const f32x4* cbr = (const f32x4*)cb + bi * 16 + half * 8;
    f32x4* op = (f32x4*)out + (rowblk + row_l) * 16 + half * 8;
    #pragma unroll
    for (int j = 0; j < 8; ++j) op[j] = cbr[j];
    float lossx = half == 0
        ? (128.0f - __builtin_bit_cast(float, kf & kmask)) : 0.0f;
    #pragma unroll
    for (int w = 32; w >= 1; w >>= 1) lossx += __shfl_xor(lossx, w, 64);
    if (lane == 0) sml[wv] = lossx;
  }
  __syncthreads();
  if (tid == 0) {
    const double t = (double)(sml[0] + sml[1] + sml[2] + sml[3]) * (1.0 / 512.0)
                   + (double)(smz[0] + smz[1]);
    atomicAdd(accum, t);
  }
}

// ---------------- kernel 3: finalize loss scalar ------------------------------
__global__ void vq_finalize(const double* __restrict__ accum,
                            float* __restrict__ out_loss) {
  out_loss[0] = (float)(1.25 * (*accum) / (double)(N_TOKENS * (size_t)DIM));
}

extern "C" void kernel_launch(void* const* d_in, const int* in_sizes, int n_in,
                              void* d_out, int out_size, void* d_ws, size_t ws_size,
                              hipStream_t stream) {
  const float* z = (const float*)d_in[0];
  const float* cb = (const float*)d_in[1];
  float* out = (float*)d_out;
  char* ws = (char*)d_ws;

  // workspace layout (135176 bytes used)
  unsigned short* ch = (unsigned short*)(ws);        // 128 KB bf16 codebook*1024
  float* ca2 = (float*)(ws + 131072);                // 4 KB   128 - ||E'||^2/2048
  double* accum = (double*)(ws + 135168);            // 8 B    loss accumulator

  vq_prep<<<256, 256, 0, stream>>>(cb, ch, ca2, accum);
  vq_argmin<<<1024, 256, 0, stream>>>(z, ch, ca2, cb, out, accum);
  vq_finalize<<<1, 1, 0, stream>>>(accum, out + (size_t)N_TOKENS * DIM);
}

// Round 5
// 35.542 us; speedup vs baseline: 1.3779x; 1.3779x over previous
//
#include <hip/hip_runtime.h>

// VectorQuantizer on MI355X (gfx950) — v5 "persistent codebook".
// out[0 .. 8388607] = codebook[argmin_k ||z - E_k||^2]   (f32)
// out[8388608]      = 1.25 * mean((z_q - z)^2)           (f32)
//
// Score: maximize  s + ca,  s = z.(1024 E_k) via bf16 MFMA, ca = 128 -
// ||1024 E_k||^2/2048 as the MFMA C-operand.  Key = (bits(s+ca) & 0xFFFFFC00)
// | (1023-col); u32 max = argmax + earliest-col tie-break (np.argmin rule).
// Loss fused: ||q-z||^2_row = ||z||^2 + (128 - v*)/512.
//
// v5 structure: 256 blocks x 512 threads, 1 block/CU (132 KB dynamic LDS).
// ENTIRE bf16 codebook staged into LDS once (XOR-swizzled via pre-swizzled
// global source; LDS dest linear per global_load_lds rules).  Each wave owns
// 64 rows exclusively and sweeps all 1024 codes from LDS with ZERO barriers
// (2 passes x 32 rows; pass-1 z loads + pass-0 out writes overlap sweeps).
// No barrier-staged inner loop at all — that structure measured 79% idle.

typedef __attribute__((ext_vector_type(8))) short bf16x8;
typedef __attribute__((ext_vector_type(4))) float f32x4;

#define N_TOKENS 131072
#define DIM 64
#define DYN_LDS 135168   // 128 KB codebook + 4 KB ca

__device__ __forceinline__ short f32_bf16(float f) {
  unsigned u = __builtin_bit_cast(unsigned, f);
  unsigned r = u + 0x7FFFu + ((u >> 16) & 1u);   // round-to-nearest-even
  return (short)(r >> 16);
}

// ---------------- kernel 1: codebook prep -------------------------------------
__global__ __launch_bounds__(256) void vq_prep(
    const float* __restrict__ cb, unsigned short* __restrict__ ch,
    float* __restrict__ ca2) {
  const int lane = threadIdx.x & 63;
  const int wv = threadIdx.x >> 6;
  const int code = blockIdx.x * 4 + wv;      // 256 blocks * 4 waves = 1024 codes
  const float e = cb[code * DIM + lane] * 1024.0f;   // exact pow2 scale
  ch[code * DIM + lane] = (unsigned short)f32_bf16(e);
  float sq = e * e;
  #pragma unroll
  for (int w = 32; w >= 1; w >>= 1) sq += __shfl_xor(sq, w, 64);
  if (lane == 0) ca2[code] = 128.0f - sq * (1.0f / 2048.0f);
}

// ---------------- kernel 2: persistent-codebook argmin + gather + loss --------
__global__ __launch_bounds__(512, 2) void vq_argmin(
    const float* __restrict__ z, const unsigned short* __restrict__ ch,
    const float* __restrict__ ca2, const float* __restrict__ cb,
    float* __restrict__ out, double* __restrict__ part) {
  extern __shared__ char lds[];
  unsigned short* Bs = (unsigned short*)lds;       // [1024 codes][64 dims], swizzled
  float* ca_s = (float*)(lds + 131072);            // [1024]
  __shared__ double sml[8];

  const int tid = threadIdx.x, lane = tid & 63, wv = tid >> 6;
  const int g = lane >> 4, c15 = lane & 15, sw = c15 & 7;
  const size_t wrow = (size_t)blockIdx.x * 512 + (size_t)wv * 64;  // wave's rows
  const unsigned kmask = 0xFFFFFC00u;

  // ---- stage whole codebook (+ca) into LDS; source XOR-swizzled, dest linear
  #pragma unroll
  for (int q = 0; q < 16; ++q) {
    const int chunk = q * 512 + tid;           // 16B chunk id, 0..8191
    const int code = chunk >> 3, c = chunk & 7;
    __builtin_amdgcn_global_load_lds(
        (const __attribute__((address_space(1))) unsigned int*)
            (ch + code * DIM + ((c ^ (code & 7)) << 3)),
        (__attribute__((address_space(3))) unsigned int*)(Bs + chunk * 8),
        16, 0, 0);
  }
  if (tid < 256)
    __builtin_amdgcn_global_load_lds(
        (const __attribute__((address_space(1))) unsigned int*)(ca2 + tid * 4),
        (__attribute__((address_space(3))) unsigned int*)(ca_s + tid * 4),
        16, 0, 0);

  // ---- pass-0 A loads (rows wrow..+31), raw f32, overlap staging drain
  f32x4 a0[2][2][2];                           // [m][kk][half]
  const float* zb = z + wrow * DIM;
  #pragma unroll
  for (int m = 0; m < 2; ++m)
    #pragma unroll
    for (int kk = 0; kk < 2; ++kk) {
      const float* p = zb + (m * 16 + c15) * DIM + kk * 32 + g * 8;
      a0[m][kk][0] = *(const f32x4*)p;
      a0[m][kk][1] = *(const f32x4*)(p + 4);
    }

  __syncthreads();   // codebook + ca resident (single full drain of the kernel)

  float zsq = 0.0f;
  auto convA = [&](f32x4 (&ar)[2][2][2], bf16x8 (&ah)[2][2]) {
    #pragma unroll
    for (int m = 0; m < 2; ++m)
      #pragma unroll
      for (int kk = 0; kk < 2; ++kk)
        #pragma unroll
        for (int j = 0; j < 4; ++j) {
          const float v0 = ar[m][kk][0][j], v1 = ar[m][kk][1][j];
          ah[m][kk][j]     = f32_bf16(v0);
          ah[m][kk][j + 4] = f32_bf16(v1);
          zsq += v0 * v0 + v1 * v1;
        }
  };

  // sweep all 1024 codes from LDS for one 32-row pass; returns loss partial
  auto sweep_epi = [&](bf16x8 (&ah)[2][2], int p) -> float {
    unsigned best[2][4];
    #pragma unroll
    for (int m = 0; m < 2; ++m)
      #pragma unroll
      for (int r = 0; r < 4; ++r) best[m][r] = 0u;
    const char* bsp = (const char*)Bs;
    const int bx0 = ((0 * 4 + g) ^ sw) << 4;   // kk=0 chunk slot (swizzled)
    const int bx1 = ((1 * 4 + g) ^ sw) << 4;   // kk=1 chunk slot
    #pragma unroll 2
    for (int t = 0; t < 32; ++t) {
      bf16x8 bf[2][2];
      #pragma unroll
      for (int n = 0; n < 2; ++n) {
        const int rowb = (t * 32 + n * 16 + c15) * 128;
        bf[n][0] = *(const bf16x8*)(bsp + rowb + bx0);
        bf[n][1] = *(const bf16x8*)(bsp + rowb + bx1);
      }
      #pragma unroll
      for (int n = 0; n < 2; ++n) {
        const float can = ca_s[t * 32 + n * 16 + c15];
        const f32x4 cv = {can, can, can, can};
        const unsigned cc = 1023u - (unsigned)(t * 32 + n * 16 + c15);
        #pragma unroll
        for (int m = 0; m < 2; ++m) {
          f32x4 acc = __builtin_amdgcn_mfma_f32_16x16x32_bf16(
              ah[m][0], bf[n][0], cv, 0, 0, 0);
          acc = __builtin_amdgcn_mfma_f32_16x16x32_bf16(
              ah[m][1], bf[n][1], acc, 0, 0, 0);
          #pragma unroll
          for (int r = 0; r < 4; ++r) {
            const unsigned key =
                (__builtin_bit_cast(unsigned, acc[r]) & kmask) | cc;  // v_and_or
            best[m][r] = key > best[m][r] ? key : best[m][r];         // v_max_u32
          }
        }
      }
    }
    // epilogue: in-wave winner resolve (rows exclusive), gather cb -> out
    float lossx = 0.0f;
    const f32x4* cb4 = (const f32x4*)cb;
    f32x4* out4 = (f32x4*)out;
    #pragma unroll
    for (int m = 0; m < 2; ++m)
      #pragma unroll
      for (int r = 0; r < 4; ++r) {
        unsigned bk = best[m][r];
        #pragma unroll
        for (int w = 1; w < 16; w <<= 1) {
          const unsigned ob = (unsigned)__shfl_xor((int)bk, w, 64);
          bk = ob > bk ? ob : bk;
        }
        const int row = p * 32 + m * 16 + g * 4 + r;   // within wave's 64
        const int bi = 1023 - (int)(bk & 1023u);
        out4[(wrow + row) * 16 + c15] = cb4[bi * 16 + c15];
        if (c15 == 0) lossx += 128.0f - __builtin_bit_cast(float, bk & kmask);
      }
    return lossx;
  };

  // ---- pass 0: convert A0, issue pass-1 loads, sweep
  bf16x8 ah[2][2];
  convA(a0, ah);
  f32x4 a1[2][2][2];
  #pragma unroll
  for (int m = 0; m < 2; ++m)
    #pragma unroll
    for (int kk = 0; kk < 2; ++kk) {
      const float* p = zb + (32 + m * 16 + c15) * DIM + kk * 32 + g * 8;
      a1[m][kk][0] = *(const f32x4*)p;
      a1[m][kk][1] = *(const f32x4*)(p + 4);
    }
  float lossx = sweep_epi(ah, 0);

  // ---- pass 1
  convA(a1, ah);
  lossx += sweep_epi(ah, 1);

  // ---- per-block loss partial (deterministic; no atomics)
  float psum = zsq + lossx * (1.0f / 512.0f);
  #pragma unroll
  for (int w = 32; w >= 1; w >>= 1) psum += __shfl_xor(psum, w, 64);
  if (lane == 0) sml[wv] = (double)psum;
  __syncthreads();
  if (tid == 0) {
    double t = 0.0;
    #pragma unroll
    for (int i = 0; i < 8; ++i) t += sml[i];
    part[blockIdx.x] = t;
  }
}

// ---------------- kernel 3: finalize loss (deterministic tree) ----------------
__global__ __launch_bounds__(256) void vq_finalize(
    const double* __restrict__ part, float* __restrict__ out_loss) {
  __shared__ double s[4];
  const int tid = threadIdx.x, lane = tid & 63, wv = tid >> 6;
  double v = part[tid];
  #pragma unroll
  for (int w = 32; w >= 1; w >>= 1) v += __shfl_xor(v, w, 64);
  if (lane == 0) s[wv] = v;
  __syncthreads();
  if (tid == 0)
    out_loss[0] = (float)(1.25 * (s[0] + s[1] + s[2] + s[3]) /
                          ((double)N_TOKENS * (double)DIM));
}

extern "C" void kernel_launch(void* const* d_in, const int* in_sizes, int n_in,
                              void* d_out, int out_size, void* d_ws, size_t ws_size,
                              hipStream_t stream) {
  const float* z = (const float*)d_in[0];
  const float* cb = (const float*)d_in[1];
  float* out = (float*)d_out;
  char* ws = (char*)d_ws;

  // workspace layout (137216 bytes used)
  unsigned short* ch = (unsigned short*)(ws);        // 128 KB bf16 codebook*1024
  float* ca2 = (float*)(ws + 131072);                // 4 KB   128 - ||E'||^2/2048
  double* part = (double*)(ws + 135168);             // 2 KB   per-block loss partials

  (void)hipFuncSetAttribute((const void*)vq_argmin,
                            hipFuncAttributeMaxDynamicSharedMemorySize, DYN_LDS);

  vq_prep<<<256, 256, 0, stream>>>(cb, ch, ca2);
  vq_argmin<<<256, 512, DYN_LDS, stream>>>(z, ch, ca2, cb, out, part);
  vq_finalize<<<1, 256, 0, stream>>>(part, out + (size_t)N_TOKENS * DIM);
}